// Round 7
// baseline (129.498 us; speedup 1.0000x reference)
//
#include <hip/hip_runtime.h>
#include <math.h>

// RansacRouting: B=32, I=1152, O=10, D=16, H=10, S=922
// R7: one kernel, one block per (b,o,h-pair) = 1600 blocks, 256 threads.
// Each thread holds 4-5 u-rows in registers (single strided read of u).
// Block scatters only its pair's 1844 sidx entries. One Mu phase + loss
// for 2 hypotheses; cross-block argmin via agent-scope muw/atomicMin/counter
// (5 blocks per (b,o); the 5th writes the winner's Mu to out).

#define B_ 32
#define I_ 1152
#define O_ 10
#define H_ 10
#define S_ 922
#define D_ 16
#define NT 256

// ws layout (bytes): muw[320][10][16] f32 | winner[320] u64 | counter[320] i32
#define MU_OFF  0u
#define WIN_OFF 204800u
#define CNT_OFF 207360u

// ---- wave64 sum via DPP (VALU pipe) -- result valid in lane 63 ----
template <int CTRL, int ROWM>
static __device__ __forceinline__ float dpp_f(float v) {
    return __int_as_float(__builtin_amdgcn_update_dpp(
        0, __float_as_int(v), CTRL, ROWM, 0xf, true));
}
static __device__ __forceinline__ float wave_sum_f32(float v) {
    v += dpp_f<0x111, 0xf>(v);
    v += dpp_f<0x112, 0xf>(v);
    v += dpp_f<0x114, 0xf>(v);
    v += dpp_f<0x118, 0xf>(v);
    v += dpp_f<0x142, 0xa>(v);
    v += dpp_f<0x143, 0xc>(v);
    return v;
}
template <int CTRL, int ROWM>
static __device__ __forceinline__ double dpp_d(double v) {
    long long x = __double_as_longlong(v);
    int lo = (int)(unsigned)(x & 0xffffffffLL);
    int hi = (int)(x >> 32);
    lo = __builtin_amdgcn_update_dpp(0, lo, CTRL, ROWM, 0xf, true);
    hi = __builtin_amdgcn_update_dpp(0, hi, CTRL, ROWM, 0xf, true);
    return __longlong_as_double((long long)(unsigned)lo | ((long long)hi << 32));
}
static __device__ __forceinline__ double wave_sum_f64(double v) {
    v += dpp_d<0x111, 0xf>(v);
    v += dpp_d<0x112, 0xf>(v);
    v += dpp_d<0x114, 0xf>(v);
    v += dpp_d<0x118, 0xf>(v);
    v += dpp_d<0x142, 0xa>(v);
    v += dpp_d<0x143, 0xc>(v);
    return v;
}

__global__ __launch_bounds__(NT) void ransac_pair(
    const float* __restrict__ up,               // [B,I,O,D]
    const int*   __restrict__ sidx,             // [B,S,O,H]
    float*       __restrict__ muw,              // ws
    unsigned long long* __restrict__ winner,    // ws, init 0xFF..
    int*         __restrict__ counter,          // ws, init -1
    float*       __restrict__ out)              // [B,O,D]
{
    __shared__ unsigned rowmask[I_];   // 2-bit membership per row (this pair)
    __shared__ float    red[4][34];
    __shared__ float    muL[2][D_];
    __shared__ double   lred[2][4];
    __shared__ int      lastf;

    // XCD swizzle: the 50 (o,hp)-blocks of one b share an XCD
    const int g   = blockIdx.x;            // [0,1600)
    const int xcd = g & 7;
    const int r   = g >> 3;                // [0,200)
    const int bhi = r / 50;
    const int rem = r - 50 * bhi;          // [0,50)
    const int o   = rem / 5;
    const int hp  = rem - 5 * o;
    const int b   = bhi * 8 + xcd;
    const int bo  = b * O_ + o;
    const int h0  = 2 * hp;

    const int tid  = threadIdx.x;
    const int lane = tid & 63;
    const int wv   = tid >> 6;
    const bool has5 = (wv < 2);            // waves 0,1 own the 5th row (uniform)

    for (int j = tid; j < I_; j += NT) rowmask[j] = 0u;

    // --- load this thread's rows into registers (64B contiguous per row) ---
    const float* ub = up + (((size_t)b * I_) * O_ + o) * D_;
    float u[5][D_];
    #pragma unroll
    for (int k = 0; k < 4; ++k) {
        const float4* p = (const float4*)(ub + (size_t)(tid + 256 * k) * (O_ * D_));
        float4 a = p[0], q = p[1], c = p[2], e = p[3];
        u[k][0]=a.x; u[k][1]=a.y; u[k][2]=a.z; u[k][3]=a.w;
        u[k][4]=q.x; u[k][5]=q.y; u[k][6]=q.z; u[k][7]=q.w;
        u[k][8]=c.x; u[k][9]=c.y; u[k][10]=c.z; u[k][11]=c.w;
        u[k][12]=e.x; u[k][13]=e.y; u[k][14]=e.z; u[k][15]=e.w;
    }
    if (has5) {
        const float4* p = (const float4*)(ub + (size_t)(tid + 1024) * (O_ * D_));
        float4 a = p[0], q = p[1], c = p[2], e = p[3];
        u[4][0]=a.x; u[4][1]=a.y; u[4][2]=a.z; u[4][3]=a.w;
        u[4][4]=q.x; u[4][5]=q.y; u[4][6]=q.z; u[4][7]=q.w;
        u[4][8]=c.x; u[4][9]=c.y; u[4][10]=c.z; u[4][11]=c.w;
        u[4][12]=e.x; u[4][13]=e.y; u[4][14]=e.z; u[4][15]=e.w;
    } else {
        #pragma unroll
        for (int d = 0; d < D_; ++d) u[4][d] = 0.f;
    }
    __syncthreads();   // rowmask zeroed

    // --- scatter membership for THIS pair only (1844 adjacent-int reads) ---
    const int* sb = sidx + (size_t)b * (S_ * O_ * H_) + o * H_ + h0;
    for (int j = tid; j < 2 * S_; j += NT) {
        int s = j >> 1, p = j & 1;
        int idx = sb[(size_t)s * (O_ * H_) + p];
        atomicOr(&rowmask[idx], 1u << p);
    }
    __syncthreads();

    unsigned m[5];
    #pragma unroll
    for (int k = 0; k < 4; ++k) m[k] = rowmask[tid + 256 * k];
    m[4] = has5 ? rowmask[tid + 1024] : 0u;

    float vn[5], usq[5];
    #pragma unroll
    for (int k = 0; k < 5; ++k) {
        float s = 0.f;
        #pragma unroll
        for (int d = 0; d < D_; ++d) s = fmaf(u[k][d], u[k][d], s);
        usq[k] = s;
        vn[k] = sqrtf(s);
    }

    // --- Mu accumulation for both hypotheses: acc[p*17+d], acc[p*17+16]=den ---
    float acc[34];
    #pragma unroll
    for (int v = 0; v < 34; ++v) acc[v] = 0.f;
    #pragma unroll
    for (int k = 0; k < 5; ++k) {
        float w0 = (m[k] & 1u) ? vn[k] : 0.f;
        float w1 = (m[k] & 2u) ? vn[k] : 0.f;
        #pragma unroll
        for (int d = 0; d < D_; ++d) {
            acc[d]      = fmaf(w0, u[k][d], acc[d]);
            acc[17 + d] = fmaf(w1, u[k][d], acc[17 + d]);
        }
        acc[16] += w0; acc[33] += w1;
    }
    #pragma unroll
    for (int v = 0; v < 34; ++v) acc[v] = wave_sum_f32(acc[v]);
    if (lane == 63) {
        #pragma unroll
        for (int v = 0; v < 34; ++v) red[wv][v] = acc[v];
    }
    __syncthreads();
    if (tid < 32) {
        int p = tid >> 4, e = tid & 15;
        float num = red[0][p*17+e] + red[1][p*17+e] + red[2][p*17+e] + red[3][p*17+e];
        float den = red[0][p*17+16] + red[1][p*17+16] + red[2][p*17+16] + red[3][p*17+16];
        muL[p][e] = num / den;
    }
    __syncthreads();

    // --- loss for both hypotheses from registers ---
    float mu[2][D_], musq[2];
    #pragma unroll
    for (int p = 0; p < 2; ++p) {
        float s = 0.f;
        #pragma unroll
        for (int d = 0; d < D_; ++d) {
            mu[p][d] = muL[p][d];
            s = fmaf(mu[p][d], mu[p][d], s);
        }
        musq[p] = s;
    }
    double lacc[2] = {0.0, 0.0};
    #pragma unroll
    for (int k = 0; k < 5; ++k) {
        float dot0 = 0.f, dot1 = 0.f;
        #pragma unroll
        for (int d = 0; d < D_; ++d) {
            dot0 = fmaf(u[k][d], mu[0][d], dot0);
            dot1 = fmaf(u[k][d], mu[1][d], dot1);
        }
        float d20 = fmaf(-2.f, dot0, usq[k] + musq[0]);
        float d21 = fmaf(-2.f, dot1, usq[k] + musq[1]);
        if (k < 4 || has5) {
            lacc[0] += (double)sqrtf(fmaxf(d20, 0.f));
            lacc[1] += (double)sqrtf(fmaxf(d21, 0.f));
        }
    }
    lacc[0] = wave_sum_f64(lacc[0]);
    lacc[1] = wave_sum_f64(lacc[1]);
    if (lane == 63) { lred[0][wv] = lacc[0]; lred[1][wv] = lacc[1]; }

    // --- publish Mu (agent scope) ---
    if (tid < 32) {
        int p = tid >> 4, e = tid & 15;
        __hip_atomic_store(&muw[((size_t)bo * H_ + h0 + p) * D_ + e],
                           muL[p][e],
                           __ATOMIC_RELAXED, __HIP_MEMORY_SCOPE_AGENT);
    }
    __syncthreads();   // drains stores; lred visible

    if (tid == 0) {
        #pragma unroll
        for (int p = 0; p < 2; ++p) {
            double L = lred[p][0] + lred[p][1] + lred[p][2] + lred[p][3];
            unsigned long long pk =
                (((unsigned long long)__double_as_longlong(L)) & ~0xFULL)
                | (unsigned)(h0 + p);
            atomicMin(&winner[bo], pk);
        }
        int old = __hip_atomic_fetch_add(&counter[bo], 1,
                                         __ATOMIC_ACQ_REL, __HIP_MEMORY_SCOPE_AGENT);
        lastf = (old == 3);   // counter init -1; 5th arrival sees 3
    }
    __syncthreads();

    if (lastf && tid < D_) {
        unsigned long long w = __hip_atomic_load(&winner[bo],
                                __ATOMIC_ACQUIRE, __HIP_MEMORY_SCOPE_AGENT);
        int hs = (int)(w & 0xF);
        float v = __hip_atomic_load(&muw[((size_t)bo * H_ + hs) * D_ + tid],
                                    __ATOMIC_RELAXED, __HIP_MEMORY_SCOPE_AGENT);
        out[(size_t)bo * D_ + tid] = v;
    }
}

extern "C" void kernel_launch(void* const* d_in, const int* in_sizes, int n_in,
                              void* d_out, int out_size, void* d_ws, size_t ws_size,
                              hipStream_t stream) {
    const float* up   = (const float*)d_in[0];
    const int*   sidx = (const int*)d_in[1];
    float*       out  = (float*)d_out;

    float* muw = (float*)((char*)d_ws + MU_OFF);
    unsigned long long* winner = (unsigned long long*)((char*)d_ws + WIN_OFF);
    int* counter = (int*)((char*)d_ws + CNT_OFF);

    // winner -> 0xFF.. (> any packed positive double), counter -> -1
    hipMemsetAsync((char*)d_ws + WIN_OFF, 0xFF, 2560 + 1280, stream);

    ransac_pair<<<1600, NT, 0, stream>>>(up, sidx, muw, winner, counter, out);
}